// Round 1
// baseline (457.083 us; speedup 1.0000x reference)
//
#include <hip/hip_runtime.h>

#define G_VOX 68921      // 41^3
#define NWORDS 2176      // >= ceil(69632/32), covers scan range; extra words unused
#define NEGV (-1.0e9f)
#define VTH (-1.0e8f)

__global__ __launch_bounds__(256) void peaks_kernel(
    const float* __restrict__ density,   // [512, G]
    const float* __restrict__ grid_xyz,  // [G, 3]
    const float* __restrict__ Rm,        // [1,128,3,3]
    const float* __restrict__ tp,        // [1,128,3]
    const float* __restrict__ nmask,     // [1,128]
    float* __restrict__ out)
{
    __shared__ unsigned int smask[NWORDS];
    __shared__ float rv[4];
    __shared__ int   ri[4];
    __shared__ float pval[4];
    __shared__ int   pidx[4];
    __shared__ int   pcoord[3];

    const int tid = threadIdx.x;
    const int nc  = blockIdx.x;          // 0..511  (n*4 + c)
    const int n   = nc >> 2;
    const float* dens = density + (size_t)nc * G_VOX;

    // ---- Phase A: build sphere bitmask in LDS via ballot ----
    // Replicates np.linalg.norm(grid_xyz, axis=-1) <= 6.0 bit-exactly:
    // f32 squares, sequential f32 add, correctly-rounded sqrt, no FMA.
    for (int it = 0; it < 270; ++it) {
        int idx = it * 256 + tid;
        bool bit = false;
        if (idx < G_VOX) {
            float gx = grid_xyz[idx * 3 + 0];
            float gy = grid_xyz[idx * 3 + 1];
            float gz = grid_xyz[idx * 3 + 2];
            float s  = __fadd_rn(__fadd_rn(__fmul_rn(gx, gx), __fmul_rn(gy, gy)),
                                 __fmul_rn(gz, gz));
            bit = (__fsqrt_rn(s) <= 6.0f);
        }
        unsigned long long bal = __ballot(bit);
        int lane  = tid & 63;
        int wbase = it * 8 + (tid >> 6) * 2;
        if (lane == 0)       smask[wbase]     = (unsigned int)bal;
        else if (lane == 32) smask[wbase + 1] = (unsigned int)(bal >> 32);
    }
    __syncthreads();

    const int shift = (tid & 7) * 4;     // bit offset of this thread's 4 elements

    // ---- Phase B: K=4 rounds of masked argmax + cube suppression ----
    for (int p = 0; p < 4; ++p) {
        float bv = -INFINITY;
        int   bi = 0x7FFFFFFF;
        for (int it = 0; it < 68; ++it) {
            const int e = it * 1024 + (tid << 2);
            const unsigned int bits = smask[(tid >> 3) + it * 32] >> shift;
            if (e + 4 <= G_VOX) {
                float v0 = dens[e + 0];
                float v1 = dens[e + 1];
                float v2 = dens[e + 2];
                float v3 = dens[e + 3];
                v0 = (bits & 1u) ? v0 : NEGV;
                v1 = (bits & 2u) ? v1 : NEGV;
                v2 = (bits & 4u) ? v2 : NEGV;
                v3 = (bits & 8u) ? v3 : NEGV;
                if (v0 > bv) { bv = v0; bi = e; }
                if (v1 > bv) { bv = v1; bi = e + 1; }
                if (v2 > bv) { bv = v2; bi = e + 2; }
                if (v3 > bv) { bv = v3; bi = e + 3; }
            } else {
                for (int q = 0; q < 4; ++q) {
                    if (e + q < G_VOX) {
                        float v = dens[e + q];
                        v = ((bits >> q) & 1u) ? v : NEGV;
                        if (v > bv) { bv = v; bi = e + q; }
                    }
                }
            }
        }

        // wave (64-lane) argmax reduce, tie-break lowest index (argmax first-hit)
        for (int off = 32; off > 0; off >>= 1) {
            float ov = __shfl_down(bv, off);
            int   oi = __shfl_down(bi, off);
            if (ov > bv || (ov == bv && oi < bi)) { bv = ov; bi = oi; }
        }
        if ((tid & 63) == 0) { rv[tid >> 6] = bv; ri[tid >> 6] = bi; }
        __syncthreads();
        if (tid == 0) {
            for (int wv = 1; wv < 4; ++wv) {
                if (rv[wv] > bv || (rv[wv] == bv && ri[wv] < bi)) { bv = rv[wv]; bi = ri[wv]; }
            }
            pval[p] = bv;
            pidx[p] = bi;
            int pi = bi / 1681;
            int rr = bi - pi * 1681;
            int pj = rr / 41;
            pcoord[0] = pi; pcoord[1] = pj; pcoord[2] = rr - pj * 41;
        }
        __syncthreads();

        // suppression: clear the 7x7x7 Chebyshev cube from the bitmask
        if (p < 3 && pval[p] > VTH) {
            if (tid < 49) {
                int di = tid / 7 - 3, dj = tid % 7 - 3;
                int ii = pcoord[0] + di, jj = pcoord[1] + dj;
                if (ii >= 0 && ii <= 40 && jj >= 0 && jj <= 40) {
                    int k0 = pcoord[2] - 3; if (k0 < 0)  k0 = 0;
                    int k1 = pcoord[2] + 3; if (k1 > 40) k1 = 40;
                    int b0  = ii * 1681 + jj * 41 + k0;
                    int cnt = k1 - k0 + 1;
                    unsigned long long m = ((1ull << cnt) - 1ull) << (b0 & 31);
                    int w0 = b0 >> 5;
                    atomicAnd(&smask[w0], ~(unsigned int)m);
                    unsigned int hi = (unsigned int)(m >> 32);
                    if (hi) atomicAnd(&smask[w0 + 1], ~hi);
                }
            }
        }
        __syncthreads();
    }

    // ---- Phase C: epilogue — one peak per thread (k = tid) ----
    if (tid < 4) {
        const int k   = tid;
        const float val = pval[k];
        const int   idx = pidx[k];
        const bool valid = val > VTH;
        float gx = 0.0f, gy = 0.0f, gz = 0.0f;
        if (valid) {
            gx = grid_xyz[idx * 3 + 0];
            gy = grid_xyz[idx * 3 + 1];
            gz = grid_xyz[idx * 3 + 2];
        }
        const float nm = nmask[n];
        const float* R = Rm + n * 9;
        const float* t = tp + n * 3;
        float wx = R[0] * gx + R[1] * gy + R[2] * gz + t[0];
        float wy = R[3] * gx + R[4] * gy + R[5] * gz + t[1];
        float wz = R[6] * gx + R[7] * gy + R[8] * gz + t[2];

        const size_t o3 = ((size_t)nc * 4 + k) * 3;
        // coords_local [1,128,4,4,3] at 0
        out[o3 + 0] = gx * nm;
        out[o3 + 1] = gy * nm;
        out[o3 + 2] = gz * nm;
        // coords_global at 6144
        out[6144 + o3 + 0] = wx * nm;
        out[6144 + o3 + 1] = wy * nm;
        out[6144 + o3 + 2] = wz * nm;
        // scores [1,128,4,4] at 12288
        const size_t o1 = (size_t)nc * 4 + k;
        out[12288 + o1] = (valid ? val : NEGV) * nm;
        // mask [1,128,4,4] at 14336 (bool as 0.0/1.0)
        out[14336 + o1] = (valid && nm != 0.0f) ? 1.0f : 0.0f;
    }
}

extern "C" void kernel_launch(void* const* d_in, const int* in_sizes, int n_in,
                              void* d_out, int out_size, void* d_ws, size_t ws_size,
                              hipStream_t stream) {
    const float* density  = (const float*)d_in[0];  // [1,128,4,G] f32
    const float* grid_xyz = (const float*)d_in[1];  // [G,3] f32
    // d_in[2] sphere_mask (bool) -- recomputed on device instead
    // d_in[3] coords_int -- not needed (i,j,k derived from linear index)
    const float* Rm    = (const float*)d_in[4];     // [1,128,3,3] f32
    const float* tpos  = (const float*)d_in[5];     // [1,128,3] f32
    const float* nmask = (const float*)d_in[6];     // [1,128] f32
    float* out = (float*)d_out;                     // 16384 f32

    peaks_kernel<<<dim3(512), dim3(256), 0, stream>>>(density, grid_xyz, Rm, tpos, nmask, out);
}

// Round 2
// 299.637 us; speedup vs baseline: 1.5255x; 1.5255x over previous
//
#include <hip/hip_runtime.h>

#define G_VOX 68921       // 41^3
#define SEG   64
#define NSEG  1077        // ceil(68921/64); 1077*64 = 68928
#define MWORDS 2160       // 32-bit mask words covering 69120 bits
#define NEGV (-1.0e9f)
#define VTH  (-1.0e8f)

// ---------------- Kernel 0: sphere bitmask -> ws ----------------
__global__ __launch_bounds__(256) void build_mask(
    const float* __restrict__ grid_xyz, unsigned int* __restrict__ mask)
{
    int idx = blockIdx.x * 256 + threadIdx.x;        // 0..69119
    bool bit = false;
    if (idx < G_VOX) {
        float gx = grid_xyz[idx * 3 + 0];
        float gy = grid_xyz[idx * 3 + 1];
        float gz = grid_xyz[idx * 3 + 2];
        float s  = __fadd_rn(__fadd_rn(__fmul_rn(gx, gx), __fmul_rn(gy, gy)),
                             __fmul_rn(gz, gz));
        bit = (__fsqrt_rn(s) <= 6.0f);               // bit-matches np.linalg.norm <= 6
    }
    unsigned long long bal = __ballot(bit);
    int lane = threadIdx.x & 63;
    if (lane == 0)       mask[idx >> 5] = (unsigned int)bal;
    else if (lane == 32) mask[idx >> 5] = (unsigned int)(bal >> 32);
}

// ---------------- Kernel 1: per-segment masked argmax ----------------
// One wave per segment (grid-stride). The single HBM pass over density.
__global__ __launch_bounds__(256) void seg_max(
    const float* __restrict__ density, const unsigned int* __restrict__ mask,
    float* __restrict__ svals, int* __restrict__ sidxs)
{
    const int nc   = blockIdx.x;                       // 0..511
    const int lane = threadIdx.x & 63;
    const int gw   = blockIdx.y * 4 + (threadIdx.x >> 6);
    const int stride = gridDim.y * 4;
    const float* dens = density + (size_t)nc * G_VOX;

    for (int s = gw; s < NSEG; s += stride) {
        int idx = s * SEG + lane;
        float v = NEGV;
        if (idx < G_VOX) {
            float d = dens[idx];
            unsigned int w = mask[idx >> 5];
            v = ((w >> (idx & 31)) & 1u) ? d : NEGV;
        }
        int bi = idx;
        for (int off = 32; off > 0; off >>= 1) {
            float ov = __shfl_down(v, off);
            int   oi = __shfl_down(bi, off);
            if (ov > v || (ov == v && oi < bi)) { v = ov; bi = oi; }
        }
        if (lane == 0) {
            svals[nc * NSEG + s] = v;
            sidxs[nc * NSEG + s] = bi;
        }
    }
}

// ---------------- Kernel 2: K rounds of argmax + NMS on segment table ----------------
__global__ __launch_bounds__(256) void pick_peaks(
    const float* __restrict__ density,
    const float* __restrict__ grid_xyz,
    const unsigned int* __restrict__ mask,
    const float* __restrict__ svals, const int* __restrict__ sidxs,
    const float* __restrict__ Rm, const float* __restrict__ tp,
    const float* __restrict__ nmask,
    float* __restrict__ out)
{
    __shared__ float sval[NSEG];
    __shared__ int   sidx[NSEG];
    __shared__ unsigned int smask[MWORDS];
    __shared__ int   flag[NSEG];
    __shared__ int   list[100];
    __shared__ int   nlist;
    __shared__ float rv[4];
    __shared__ int   ri[4];
    __shared__ float pval[4];
    __shared__ int   pidx[4];
    __shared__ int   pcoord[3];

    const int tid = threadIdx.x;
    const int nc  = blockIdx.x;
    const int n   = nc >> 2;
    const float* dens = density + (size_t)nc * G_VOX;

    for (int i = tid; i < NSEG; i += 256) {
        sval[i] = svals[nc * NSEG + i];
        sidx[i] = sidxs[nc * NSEG + i];
        flag[i] = 0;
    }
    for (int i = tid; i < MWORDS; i += 256) smask[i] = mask[i];
    __syncthreads();

    for (int p = 0; p < 4; ++p) {
        // global argmax over segment records (tie-break: lowest voxel index)
        float bv = -INFINITY;
        int   bi = 0x7FFFFFFF;
        for (int s = tid; s < NSEG; s += 256) {
            float v = sval[s];
            int   i = sidx[s];
            if (v > bv || (v == bv && i < bi)) { bv = v; bi = i; }
        }
        for (int off = 32; off > 0; off >>= 1) {
            float ov = __shfl_down(bv, off);
            int   oi = __shfl_down(bi, off);
            if (ov > bv || (ov == bv && oi < bi)) { bv = ov; bi = oi; }
        }
        if ((tid & 63) == 0) { rv[tid >> 6] = bv; ri[tid >> 6] = bi; }
        __syncthreads();
        if (tid == 0) {
            for (int wv = 1; wv < 4; ++wv) {
                if (rv[wv] > bv || (rv[wv] == bv && ri[wv] < bi)) { bv = rv[wv]; bi = ri[wv]; }
            }
            pval[p] = bv;
            pidx[p] = bi;
            int pi = bi / 1681;
            int rr = bi - pi * 1681;
            int pj = rr / 41;
            pcoord[0] = pi; pcoord[1] = pj; pcoord[2] = rr - pj * 41;
            nlist = 0;
        }
        __syncthreads();

        if (p < 3 && pval[p] > VTH) {
            // clear 7x7x7 Chebyshev cube bits; collect affected segments
            if (tid < 49) {
                int di = tid / 7 - 3, dj = tid % 7 - 3;
                int ii = pcoord[0] + di, jj = pcoord[1] + dj;
                if (ii >= 0 && ii <= 40 && jj >= 0 && jj <= 40) {
                    int k0 = pcoord[2] - 3; if (k0 < 0)  k0 = 0;
                    int k1 = pcoord[2] + 3; if (k1 > 40) k1 = 40;
                    int b0  = ii * 1681 + jj * 41 + k0;
                    int cnt = k1 - k0 + 1;
                    unsigned long long m = ((1ull << cnt) - 1ull) << (b0 & 31);
                    int w0 = b0 >> 5;
                    atomicAnd(&smask[w0], ~(unsigned int)m);
                    unsigned int hi = (unsigned int)(m >> 32);
                    if (hi) atomicAnd(&smask[w0 + 1], ~hi);
                    // mark touched segments (<=2 per row)
                    int s0 = b0 >> 6;
                    int s1 = (b0 + cnt - 1) >> 6;
                    if (atomicMax(&flag[s0], p + 1) < p + 1) {
                        int q = atomicAdd(&nlist, 1); list[q] = s0;
                    }
                    if (s1 != s0 && atomicMax(&flag[s1], p + 1) < p + 1) {
                        int q = atomicAdd(&nlist, 1); list[q] = s1;
                    }
                }
            }
            __syncthreads();
            // recompute affected segments: one wave per listed segment
            const int lane = tid & 63;
            const int wv   = tid >> 6;
            const int cnt  = nlist;
            for (int j = wv; j < cnt; j += 4) {
                int s   = list[j];
                int idx = s * SEG + lane;
                float v = NEGV;
                if (idx < G_VOX) {
                    float d = dens[idx];
                    unsigned int w = smask[idx >> 5];
                    v = ((w >> (idx & 31)) & 1u) ? d : NEGV;
                }
                int bi2 = idx;
                for (int off = 32; off > 0; off >>= 1) {
                    float ov = __shfl_down(v, off);
                    int   oi = __shfl_down(bi2, off);
                    if (ov > v || (ov == v && oi < bi2)) { v = ov; bi2 = oi; }
                }
                if (lane == 0) { sval[s] = v; sidx[s] = bi2; }
            }
        }
        __syncthreads();
    }

    // ---- epilogue: one peak per thread ----
    if (tid < 4) {
        const int k   = tid;
        const float val = pval[k];
        const int   idx = pidx[k];
        const bool valid = val > VTH;
        float gx = 0.0f, gy = 0.0f, gz = 0.0f;
        if (valid) {
            gx = grid_xyz[idx * 3 + 0];
            gy = grid_xyz[idx * 3 + 1];
            gz = grid_xyz[idx * 3 + 2];
        }
        const float nm = nmask[n];
        const float* R = Rm + n * 9;
        const float* t = tp + n * 3;
        float wx = R[0] * gx + R[1] * gy + R[2] * gz + t[0];
        float wy = R[3] * gx + R[4] * gy + R[5] * gz + t[1];
        float wz = R[6] * gx + R[7] * gy + R[8] * gz + t[2];

        const size_t o3 = ((size_t)nc * 4 + k) * 3;
        out[o3 + 0] = gx * nm;
        out[o3 + 1] = gy * nm;
        out[o3 + 2] = gz * nm;
        out[6144 + o3 + 0] = wx * nm;
        out[6144 + o3 + 1] = wy * nm;
        out[6144 + o3 + 2] = wz * nm;
        const size_t o1 = (size_t)nc * 4 + k;
        out[12288 + o1] = (valid ? val : NEGV) * nm;
        out[14336 + o1] = (valid && nm != 0.0f) ? 1.0f : 0.0f;
    }
}

extern "C" void kernel_launch(void* const* d_in, const int* in_sizes, int n_in,
                              void* d_out, int out_size, void* d_ws, size_t ws_size,
                              hipStream_t stream) {
    const float* density  = (const float*)d_in[0];  // [1,128,4,G] f32
    const float* grid_xyz = (const float*)d_in[1];  // [G,3] f32
    const float* Rm    = (const float*)d_in[4];     // [1,128,3,3] f32
    const float* tpos  = (const float*)d_in[5];     // [1,128,3] f32
    const float* nmask = (const float*)d_in[6];     // [1,128] f32
    float* out = (float*)d_out;                     // 16384 f32

    // workspace layout
    unsigned int* mask = (unsigned int*)d_ws;                         // 2160 words (8640 B)
    float* svals = (float*)((char*)d_ws + 16384);                     // 512*1077 floats
    int*   sidxs = (int*)  ((char*)d_ws + 16384 + (size_t)512 * NSEG * 4);

    build_mask<<<dim3(270), dim3(256), 0, stream>>>(grid_xyz, mask);
    seg_max<<<dim3(512, 68), dim3(256), 0, stream>>>(density, mask, svals, sidxs);
    pick_peaks<<<dim3(512), dim3(256), 0, stream>>>(density, grid_xyz, mask,
                                                    svals, sidxs, Rm, tpos, nmask, out);
}

// Round 3
// 245.032 us; speedup vs baseline: 1.8654x; 1.2228x over previous
//
#include <hip/hip_runtime.h>

#define G_VOX  68921       // 41^3
#define NSEG   272         // 17 chunks * 16 segments of 256
#define MWORDS 2176        // 32-bit mask words covering 69632 bits
#define NEGV (-1.0e9f)
#define VTH  (-1.0e8f)

__device__ __forceinline__ bool sphere_bit(const float* __restrict__ grid_xyz, int e) {
    if (e >= G_VOX) return false;
    float gx = grid_xyz[e * 3 + 0];
    float gy = grid_xyz[e * 3 + 1];
    float gz = grid_xyz[e * 3 + 2];
    float s  = __fadd_rn(__fadd_rn(__fmul_rn(gx, gx), __fmul_rn(gy, gy)),
                         __fmul_rn(gz, gz));
    return (__fsqrt_rn(s) <= 6.0f);    // bit-matches np.linalg.norm <= 6
}

// ---------------- Kernel 0: sphere masks (word form + repacked ushort form) ----------------
__global__ __launch_bounds__(256) void build_mask(
    const float* __restrict__ grid_xyz,
    unsigned int* __restrict__ mask,          // [MWORDS] natural bit order
    unsigned short* __restrict__ rm)          // [4352] bit j of rm[s*16+p] = sphere(s*256+p+16j)
{
    const int tid = threadIdx.x;
    const int lane = tid & 63;

    // phase 1: natural-order word mask
    {
        int idx = blockIdx.x * 256 + tid;     // 0..69631
        unsigned long long bal = __ballot(sphere_bit(grid_xyz, idx));
        if (lane == 0)       mask[idx >> 5] = (unsigned int)bal;
        else if (lane == 32) mask[idx >> 5] = (unsigned int)(bal >> 32);
    }
    // phase 2: repacked mask for seg_max's strided traversal
    {
        int v = blockIdx.x * 256 + tid;       // 0..69631
        int e = (v & ~255) + ((v >> 4) & 15) + 16 * (v & 15);
        unsigned long long bal = __ballot(sphere_bit(grid_xyz, e));
        if ((lane & 15) == 0)
            rm[v >> 4] = (unsigned short)((bal >> ((lane >> 4) << 4)) & 0xFFFFull);
    }
}

// ---------------- Kernel 1: per-256-segment masked argmax (single density pass) ----------------
__global__ __launch_bounds__(256) void seg_max(
    const float* __restrict__ density, const unsigned short* __restrict__ rm,
    float* __restrict__ svals, int* __restrict__ sidxs)
{
    const int nc  = blockIdx.x;               // 0..511
    const int c   = blockIdx.y;               // 0..16 (chunk of 4096 elements)
    const int tid = threadIdx.x;
    const int p   = tid & 15;
    const int sl  = tid >> 4;                 // local segment 0..15
    const int base = c * 4096 + sl * 256 + p; // element index at j=0
    const float* dens = density + (size_t)nc * G_VOX;

    const unsigned int bits = rm[c * 256 + tid];

    float bv = NEGV;
    int   bi = base;
    if (c < 16) {
        #pragma unroll
        for (int j = 0; j < 16; ++j) {
            int e = base + 16 * j;
            float d = dens[e];
            float v = ((bits >> j) & 1u) ? d : NEGV;
            if (v > bv) { bv = v; bi = e; }   // ascending e => strict > keeps first occurrence
        }
    } else {
        #pragma unroll
        for (int j = 0; j < 16; ++j) {
            int e = base + 16 * j;
            if (e < G_VOX) {
                float d = dens[e];
                float v = ((bits >> j) & 1u) ? d : NEGV;
                if (v > bv) { bv = v; bi = e; }
            }
        }
    }
    // reduce across the 16 lanes of this segment (butterfly, tie-break lowest idx)
    #pragma unroll
    for (int off = 1; off < 16; off <<= 1) {
        float ov = __shfl_xor(bv, off);
        int   oi = __shfl_xor(bi, off);
        if (ov > bv || (ov == bv && oi < bi)) { bv = ov; bi = oi; }
    }
    if (p == 0) {
        int s = c * 16 + sl;
        svals[nc * NSEG + s] = bv;
        sidxs[nc * NSEG + s] = bi;
    }
}

// ---------------- Kernel 2: K rounds of argmax + NMS on segment table ----------------
__global__ __launch_bounds__(256) void pick_peaks(
    const float* __restrict__ density,
    const float* __restrict__ grid_xyz,
    const unsigned int* __restrict__ mask,
    const float* __restrict__ svals, const int* __restrict__ sidxs,
    const float* __restrict__ Rm, const float* __restrict__ tp,
    const float* __restrict__ nmask,
    float* __restrict__ out)
{
    __shared__ float sval[NSEG];
    __shared__ int   sidx[NSEG];
    __shared__ unsigned int smask[MWORDS];
    __shared__ int   flag[NSEG];
    __shared__ int   list[128];
    __shared__ int   nlist;
    __shared__ float rv[4];
    __shared__ int   ri[4];
    __shared__ float pval[4];
    __shared__ int   pidx[4];
    __shared__ int   pcoord[3];

    const int tid = threadIdx.x;
    const int nc  = blockIdx.x;
    const int n   = nc >> 2;
    const float* dens = density + (size_t)nc * G_VOX;

    for (int i = tid; i < NSEG; i += 256) {
        sval[i] = svals[nc * NSEG + i];
        sidx[i] = sidxs[nc * NSEG + i];
        flag[i] = 0;
    }
    for (int i = tid; i < MWORDS; i += 256) smask[i] = mask[i];
    __syncthreads();

    for (int p = 0; p < 4; ++p) {
        // global argmax over segment records (tie-break: lowest voxel index)
        float bv = -INFINITY;
        int   bi = 0x7FFFFFFF;
        for (int s = tid; s < NSEG; s += 256) {
            float v = sval[s];
            int   i = sidx[s];
            if (v > bv || (v == bv && i < bi)) { bv = v; bi = i; }
        }
        for (int off = 32; off > 0; off >>= 1) {
            float ov = __shfl_down(bv, off);
            int   oi = __shfl_down(bi, off);
            if (ov > bv || (ov == bv && oi < bi)) { bv = ov; bi = oi; }
        }
        if ((tid & 63) == 0) { rv[tid >> 6] = bv; ri[tid >> 6] = bi; }
        __syncthreads();
        if (tid == 0) {
            for (int wv = 1; wv < 4; ++wv) {
                if (rv[wv] > bv || (rv[wv] == bv && ri[wv] < bi)) { bv = rv[wv]; bi = ri[wv]; }
            }
            pval[p] = bv;
            pidx[p] = bi;
            int pi = bi / 1681;
            int rr = bi - pi * 1681;
            int pj = rr / 41;
            pcoord[0] = pi; pcoord[1] = pj; pcoord[2] = rr - pj * 41;
            nlist = 0;
        }
        __syncthreads();

        if (p < 3 && pval[p] > VTH) {
            // clear 7x7x7 Chebyshev cube bits; collect affected 256-segments
            if (tid < 49) {
                int di = tid / 7 - 3, dj = tid % 7 - 3;
                int ii = pcoord[0] + di, jj = pcoord[1] + dj;
                if (ii >= 0 && ii <= 40 && jj >= 0 && jj <= 40) {
                    int k0 = pcoord[2] - 3; if (k0 < 0)  k0 = 0;
                    int k1 = pcoord[2] + 3; if (k1 > 40) k1 = 40;
                    int b0  = ii * 1681 + jj * 41 + k0;
                    int cnt = k1 - k0 + 1;
                    unsigned long long m = ((1ull << cnt) - 1ull) << (b0 & 31);
                    int w0 = b0 >> 5;
                    atomicAnd(&smask[w0], ~(unsigned int)m);
                    unsigned int hi = (unsigned int)(m >> 32);
                    if (hi) atomicAnd(&smask[w0 + 1], ~hi);
                    int s0 = b0 >> 8;
                    int s1 = (b0 + cnt - 1) >> 8;
                    if (atomicMax(&flag[s0], p + 1) < p + 1) {
                        int q = atomicAdd(&nlist, 1); list[q] = s0;
                    }
                    if (s1 != s0 && atomicMax(&flag[s1], p + 1) < p + 1) {
                        int q = atomicAdd(&nlist, 1); list[q] = s1;
                    }
                }
            }
            __syncthreads();
            // recompute affected segments: one wave per listed segment, 4 elems/lane
            const int lane = tid & 63;
            const int wv   = tid >> 6;
            const int cnt  = nlist;
            for (int j = wv; j < cnt; j += 4) {
                int s = list[j];
                float v = NEGV;
                int bi2 = s * 256 + lane * 4;
                #pragma unroll
                for (int q = 0; q < 4; ++q) {
                    int e = s * 256 + lane * 4 + q;
                    if (e < G_VOX) {
                        float d = dens[e];
                        unsigned int w = smask[e >> 5];
                        float vv = ((w >> (e & 31)) & 1u) ? d : NEGV;
                        if (vv > v) { v = vv; bi2 = e; }
                    }
                }
                for (int off = 32; off > 0; off >>= 1) {
                    float ov = __shfl_down(v, off);
                    int   oi = __shfl_down(bi2, off);
                    if (ov > v || (ov == v && oi < bi2)) { v = ov; bi2 = oi; }
                }
                if (lane == 0) { sval[s] = v; sidx[s] = bi2; }
            }
        }
        __syncthreads();
    }

    // ---- epilogue: one peak per thread ----
    if (tid < 4) {
        const int k   = tid;
        const float val = pval[k];
        const int   idx = pidx[k];
        const bool valid = val > VTH;
        float gx = 0.0f, gy = 0.0f, gz = 0.0f;
        if (valid) {
            gx = grid_xyz[idx * 3 + 0];
            gy = grid_xyz[idx * 3 + 1];
            gz = grid_xyz[idx * 3 + 2];
        }
        const float nm = nmask[n];
        const float* R = Rm + n * 9;
        const float* t = tp + n * 3;
        float wx = R[0] * gx + R[1] * gy + R[2] * gz + t[0];
        float wy = R[3] * gx + R[4] * gy + R[5] * gz + t[1];
        float wz = R[6] * gx + R[7] * gy + R[8] * gz + t[2];

        const size_t o3 = ((size_t)nc * 4 + k) * 3;
        out[o3 + 0] = gx * nm;
        out[o3 + 1] = gy * nm;
        out[o3 + 2] = gz * nm;
        out[6144 + o3 + 0] = wx * nm;
        out[6144 + o3 + 1] = wy * nm;
        out[6144 + o3 + 2] = wz * nm;
        const size_t o1 = (size_t)nc * 4 + k;
        out[12288 + o1] = (valid ? val : NEGV) * nm;
        out[14336 + o1] = (valid && nm != 0.0f) ? 1.0f : 0.0f;
    }
}

extern "C" void kernel_launch(void* const* d_in, const int* in_sizes, int n_in,
                              void* d_out, int out_size, void* d_ws, size_t ws_size,
                              hipStream_t stream) {
    const float* density  = (const float*)d_in[0];  // [1,128,4,G] f32
    const float* grid_xyz = (const float*)d_in[1];  // [G,3] f32
    const float* Rm    = (const float*)d_in[4];     // [1,128,3,3] f32
    const float* tpos  = (const float*)d_in[5];     // [1,128,3] f32
    const float* nmask = (const float*)d_in[6];     // [1,128] f32
    float* out = (float*)d_out;                     // 16384 f32

    // workspace layout
    unsigned int*   mask = (unsigned int*)d_ws;                        // 2176 words (8704 B)
    unsigned short* rm   = (unsigned short*)((char*)d_ws + 8704);      // 4352 ushort (8704 B)
    float* svals = (float*)((char*)d_ws + 17408);                      // 512*272 f32
    int*   sidxs = (int*)  ((char*)d_ws + 17408 + (size_t)512 * NSEG * 4);

    build_mask<<<dim3(272), dim3(256), 0, stream>>>(grid_xyz, mask, rm);
    seg_max<<<dim3(512, 17), dim3(256), 0, stream>>>(density, rm, svals, sidxs);
    pick_peaks<<<dim3(512), dim3(256), 0, stream>>>(density, grid_xyz, mask,
                                                    svals, sidxs, Rm, tpos, nmask, out);
}